// Round 1
// baseline (461.520 us; speedup 1.0000x reference)
//
#include <hip/hip_runtime.h>
#include <hip/hip_bf16.h>
#include <stdint.h>

#define B_ 4
#define N_ 2048
#define C_ 1024
#define H_ 16
#define D_ 64
#define TOK (B_ * N_)        // 8192 tokens
#define SCALE_Q 0.125f       // 64^-0.5

typedef __attribute__((ext_vector_type(8))) short bf16x8;        // 8 bf16 = 4 VGPRs
typedef __attribute__((ext_vector_type(4))) float f32x4;
typedef __attribute__((ext_vector_type(8))) unsigned short u16x8;
typedef __attribute__((ext_vector_type(4))) unsigned short u16x4;

__device__ __forceinline__ unsigned short f2bf(float f) {
  union { float f; unsigned u; } v; v.f = f;
  unsigned r = v.u + 0x7fffu + ((v.u >> 16) & 1u);   // RNE
  return (unsigned short)(r >> 16);
}

__device__ __forceinline__ void gload_lds16(const unsigned short* g, unsigned short* l) {
  __builtin_amdgcn_global_load_lds(
      (const __attribute__((address_space(1))) unsigned int*)g,
      (__attribute__((address_space(3))) unsigned int*)l, 16, 0, 0);
}

// ---------------- cast f32 -> bf16, 8 elems/thread ----------------
__global__ __launch_bounds__(256)
void cast_f32_bf16(const float* __restrict__ in, unsigned short* __restrict__ out, int n8) {
  int i = blockIdx.x * blockDim.x + threadIdx.x;
  const int stride = gridDim.x * blockDim.x;
  for (; i < n8; i += stride) {
    const float4* p = (const float4*)(in + (size_t)i * 8);
    float4 a = p[0], b = p[1];
    u16x8 o;
    o[0] = f2bf(a.x); o[1] = f2bf(a.y); o[2] = f2bf(a.z); o[3] = f2bf(a.w);
    o[4] = f2bf(b.x); o[5] = f2bf(b.y); o[6] = f2bf(b.z); o[7] = f2bf(b.w);
    *(u16x8*)(out + (size_t)i * 8) = o;
  }
}

// ---------------- GEMM C[M,Nc] = A[M,K] * B[Nc,K]^T  (bf16 in, m97 structure) ----
// EPI=0: Nc=3072, scatter into q(*SCALE)/k/v [B,H,N,D] bf16
// EPI=1: Nc=1024, out fp32 [M,Nc] + bias
template<int EPI>
__global__ __launch_bounds__(256)
void gemm_bt(const unsigned short* __restrict__ A,
             const unsigned short* __restrict__ Bm,
             unsigned short* __restrict__ qo, unsigned short* __restrict__ ko,
             unsigned short* __restrict__ vo,
             float* __restrict__ out, const float* __restrict__ bias)
{
  constexpr int K = 1024;
  __shared__ __attribute__((aligned(16))) unsigned short lds_a[128 * 32];
  __shared__ __attribute__((aligned(16))) unsigned short lds_b[128 * 32];
  const int tid = threadIdx.x;
  const int lane = tid & 63;
  const int w = tid >> 6;                 // wave 0..3
  const int wr = w >> 1, wc = w & 1;      // 2x2 wave grid, 64x64 each
  const int tm = blockIdx.y * 128;
  const int tn = blockIdx.x * 128;
  const int l4 = lane >> 4, l16 = lane & 15;

  f32x4 acc[4][4] = {};

  // staging: each wave fills 2 segments (16 rows x 32 cols = 1KB) of A and of B
  const int srow = lane >> 2;             // 0..15
  const int scol = (lane & 3) * 8;        // 0,8,16,24
  const unsigned short* Ab = A  + (size_t)(tm + 2 * w * 16 + srow) * K + scol;
  const unsigned short* Bb = Bm + (size_t)(tn + 2 * w * 16 + srow) * K + scol;
  unsigned short* la = lds_a + 2 * w * 512;
  unsigned short* lb = lds_b + 2 * w * 512;

  for (int k0 = 0; k0 < K; k0 += 32) {
    __syncthreads();
    gload_lds16(Ab + k0,           la);
    gload_lds16(Ab + 16 * K + k0,  la + 512);
    gload_lds16(Bb + k0,           lb);
    gload_lds16(Bb + 16 * K + k0,  lb + 512);
    asm volatile("s_waitcnt vmcnt(0)" ::: "memory");
    __syncthreads();

    bf16x8 af[4], bfr[4];
#pragma unroll
    for (int i = 0; i < 4; ++i)
      af[i] = *(const bf16x8*)&lds_a[(wr * 64 + i * 16 + l16) * 32 + l4 * 8];
#pragma unroll
    for (int i = 0; i < 4; ++i)
      bfr[i] = *(const bf16x8*)&lds_b[(wc * 64 + i * 16 + l16) * 32 + l4 * 8];
#pragma unroll
    for (int mi = 0; mi < 4; ++mi)
#pragma unroll
      for (int ni = 0; ni < 4; ++ni)
        acc[mi][ni] = __builtin_amdgcn_mfma_f32_16x16x32_bf16(af[mi], bfr[ni], acc[mi][ni], 0, 0, 0);
  }

  if (EPI == 0) {
#pragma unroll
    for (int ni = 0; ni < 4; ++ni) {
      const int c0 = tn + wc * 64 + ni * 16;       // wave-uniform, 16-aligned
      const int t  = c0 >> 10;                     // 0:q 1:k 2:v
      const int h  = (c0 >> 6) & 15;
      const int d0 = (c0 & 63) + l16;
      unsigned short* dst = (t == 0) ? qo : (t == 1) ? ko : vo;
      const float sc = (t == 0) ? SCALE_Q : 1.0f;
#pragma unroll
      for (int mi = 0; mi < 4; ++mi) {
        const int r0 = tm + wr * 64 + mi * 16 + l4 * 4;
#pragma unroll
        for (int r = 0; r < 4; ++r) {
          const int row = r0 + r;                  // token 0..8191
          const int b = row >> 11, n = row & (N_ - 1);
          dst[((size_t)(b * H_ + h) * N_ + n) * D_ + d0] = f2bf(acc[mi][ni][r] * sc);
        }
      }
    }
  } else {
#pragma unroll
    for (int ni = 0; ni < 4; ++ni) {
      const int c = tn + wc * 64 + ni * 16 + l16;
      const float bv = bias[c];
#pragma unroll
      for (int mi = 0; mi < 4; ++mi) {
        const int r0 = tm + wr * 64 + mi * 16 + l4 * 4;
#pragma unroll
        for (int r = 0; r < 4; ++r)
          out[(size_t)(r0 + r) * C_ + c] = acc[mi][ni][r] + bv;
      }
    }
  }
}

// ---------------- V [bh][n][d] -> Vt [bh][d][n] ----------------
__global__ __launch_bounds__(256)
void transpose_v(const unsigned short* __restrict__ v, unsigned short* __restrict__ vt) {
  __shared__ __attribute__((aligned(16))) unsigned short t[64][72];  // +8 pad, 8B-aligned rows
  const int bh = blockIdx.y;
  const int n0 = blockIdx.x * 64;
  const int tid = threadIdx.x;
  const unsigned short* src = v + ((size_t)bh * N_ + n0) * D_;
  for (int c = tid; c < 512; c += 256) {
    const int row = c >> 3, col = (c & 7) * 8;
    const unsigned short* s8 = src + row * 64 + col;
    *(u16x4*)&t[row][col]     = *(const u16x4*)(s8);
    *(u16x4*)&t[row][col + 4] = *(const u16x4*)(s8 + 4);
  }
  __syncthreads();
  unsigned short* dst = vt + (size_t)bh * D_ * N_ + n0;
  for (int c = tid; c < 512; c += 256) {
    const int d = c >> 3, j = (c & 7) * 8;
    u16x8 o;
#pragma unroll
    for (int jj = 0; jj < 8; ++jj) o[jj] = t[j + jj][d];
    *(u16x8*)(dst + (size_t)d * N_ + j) = o;
  }
}

// ---------------- flash attention ----------------
// grid (16 q-tiles, 64 bh), 256 threads = 4 waves x 32 q-rows. KV tile = 64.
// q pre-scaled. K,V^T read from global (L2-resident). P via per-wave swizzled LDS.
__global__ __launch_bounds__(256)
void flash_attn(const unsigned short* __restrict__ q,
                const unsigned short* __restrict__ k,
                const unsigned short* __restrict__ vt,
                unsigned short* __restrict__ out)
{
  __shared__ __attribute__((aligned(16))) unsigned short p_lds[4][32 * 64];
  const int bh = blockIdx.y;
  const int qt = blockIdx.x;
  const int tid = threadIdx.x, lane = tid & 63, w = tid >> 6;
  const int l4 = lane >> 4, l16 = lane & 15;
  const unsigned short* qb = q  + (size_t)bh * N_ * D_;
  const unsigned short* kb = k  + (size_t)bh * N_ * D_;
  const unsigned short* vb = vt + (size_t)bh * D_ * N_;
  const int q0 = qt * 128 + w * 32;

  // Q fragments in registers: A[m=l16][k = d], 2 m-frags x 2 k-steps
  bf16x8 qf[2][2];
#pragma unroll
  for (int mi = 0; mi < 2; ++mi)
#pragma unroll
    for (int ks = 0; ks < 2; ++ks)
      qf[mi][ks] = *(const bf16x8*)(qb + (size_t)(q0 + mi * 16 + l16) * D_ + ks * 32 + l4 * 8);

  f32x4 oacc[2][4] = {};
  float mrun[2][4], lrun[2][4];
#pragma unroll
  for (int mi = 0; mi < 2; ++mi)
#pragma unroll
    for (int r = 0; r < 4; ++r) { mrun[mi][r] = -1e30f; lrun[mi][r] = 0.0f; }

  char* pw = (char*)&p_lds[w][0];

  for (int kv0 = 0; kv0 < N_; kv0 += 64) {
    // S = Q K^T : [32 q x 64 kv]
    f32x4 s[2][4] = {};
#pragma unroll
    for (int ks = 0; ks < 2; ++ks) {
      bf16x8 bk[4];
#pragma unroll
      for (int nf = 0; nf < 4; ++nf)
        bk[nf] = *(const bf16x8*)(kb + (size_t)(kv0 + nf * 16 + l16) * D_ + ks * 32 + l4 * 8);
#pragma unroll
      for (int mi = 0; mi < 2; ++mi)
#pragma unroll
        for (int nf = 0; nf < 4; ++nf)
          s[mi][nf] = __builtin_amdgcn_mfma_f32_16x16x32_bf16(qf[mi][ks], bk[nf], s[mi][nf], 0, 0, 0);
    }
    // online softmax: row = mi*16 + l4*4 + r, cols spread over l16 and nf
#pragma unroll
    for (int mi = 0; mi < 2; ++mi) {
#pragma unroll
      for (int r = 0; r < 4; ++r) {
        float tmax = fmaxf(fmaxf(s[mi][0][r], s[mi][1][r]), fmaxf(s[mi][2][r], s[mi][3][r]));
        tmax = fmaxf(tmax, __shfl_xor(tmax, 1));
        tmax = fmaxf(tmax, __shfl_xor(tmax, 2));
        tmax = fmaxf(tmax, __shfl_xor(tmax, 4));
        tmax = fmaxf(tmax, __shfl_xor(tmax, 8));
        const float mold = mrun[mi][r];
        const float mnew = fmaxf(mold, tmax);
        const float scl = __expf(mold - mnew);
        mrun[mi][r] = mnew;
        const int row = mi * 16 + l4 * 4 + r;
        const int swz = (row & 7) << 4;           // XOR-swizzle bits 4-6 (G4)
        float psum = 0.0f;
#pragma unroll
        for (int nf = 0; nf < 4; ++nf) {
          const float pv = __expf(s[mi][nf][r] - mnew);
          psum += pv;
          *(unsigned short*)(pw + ((row * 128 + (nf * 16 + l16) * 2) ^ swz)) = f2bf(pv);
        }
        psum += __shfl_xor(psum, 1);
        psum += __shfl_xor(psum, 2);
        psum += __shfl_xor(psum, 4);
        psum += __shfl_xor(psum, 8);
        lrun[mi][r] = lrun[mi][r] * scl + psum;
#pragma unroll
        for (int nf = 0; nf < 4; ++nf) oacc[mi][nf][r] *= scl;
      }
    }
    // O += P V : A from swizzled LDS, B = V^T from global (contiguous 16B)
#pragma unroll
    for (int ks = 0; ks < 2; ++ks) {
      bf16x8 pa[2], vv[4];
#pragma unroll
      for (int mi = 0; mi < 2; ++mi) {
        const int row = mi * 16 + l16;
        pa[mi] = *(const bf16x8*)(pw + ((row * 128 + (ks * 32 + l4 * 8) * 2) ^ ((row & 7) << 4)));
      }
#pragma unroll
      for (int nf = 0; nf < 4; ++nf)
        vv[nf] = *(const bf16x8*)(vb + (size_t)(nf * 16 + l16) * N_ + kv0 + ks * 32 + l4 * 8);
#pragma unroll
      for (int mi = 0; mi < 2; ++mi)
#pragma unroll
        for (int nf = 0; nf < 4; ++nf)
          oacc[mi][nf] = __builtin_amdgcn_mfma_f32_16x16x32_bf16(pa[mi], vv[nf], oacc[mi][nf], 0, 0, 0);
    }
  }

  // epilogue: out[b][n][h*64+d] bf16
  const int b = bh >> 4, h = bh & 15;
#pragma unroll
  for (int mi = 0; mi < 2; ++mi) {
#pragma unroll
    for (int r = 0; r < 4; ++r) {
      const float inv = 1.0f / lrun[mi][r];
      const int rg = b * N_ + q0 + mi * 16 + l4 * 4 + r;
#pragma unroll
      for (int nf = 0; nf < 4; ++nf)
        out[(size_t)rg * C_ + h * 64 + nf * 16 + l16] = f2bf(oacc[mi][nf][r] * inv);
    }
  }
}

extern "C" void kernel_launch(void* const* d_in, const int* in_sizes, int n_in,
                              void* d_out, int out_size, void* d_ws, size_t ws_size,
                              hipStream_t stream) {
  const float* x      = (const float*)d_in[0];
  const float* w_qkv  = (const float*)d_in[1];
  const float* w_proj = (const float*)d_in[2];
  const float* b_proj = (const float*)d_in[3];
  float* out = (float*)d_out;

  char* p = (char*)d_ws;
  unsigned short* xb   = (unsigned short*)p; p += (size_t)TOK * C_ * 2;      // x bf16
  unsigned short* wqb  = (unsigned short*)p; p += (size_t)3 * C_ * C_ * 2;   // w_qkv bf16
  unsigned short* wpb  = (unsigned short*)p; p += (size_t)C_ * C_ * 2;       // w_proj bf16
  unsigned short* qbuf = (unsigned short*)p; p += (size_t)TOK * C_ * 2;      // q [B,H,N,D] (scaled)
  unsigned short* kbuf = (unsigned short*)p; p += (size_t)TOK * C_ * 2;      // k [B,H,N,D]
  unsigned short* vbuf = (unsigned short*)p; p += (size_t)TOK * C_ * 2;      // v [B,H,N,D]
  unsigned short* vtb  = (unsigned short*)p; p += (size_t)TOK * C_ * 2;      // v^T [B,H,D,N]
  unsigned short* aout = (unsigned short*)p; p += (size_t)TOK * C_ * 2;      // attn out [B*N, C]

  cast_f32_bf16<<<1024, 256, 0, stream>>>(x,      xb,  TOK * C_ / 8);
  cast_f32_bf16<<<1024, 256, 0, stream>>>(w_qkv,  wqb, 3 * C_ * C_ / 8);
  cast_f32_bf16<<<512,  256, 0, stream>>>(w_proj, wpb, C_ * C_ / 8);

  gemm_bt<0><<<dim3(24, 64), 256, 0, stream>>>(xb, wqb, qbuf, kbuf, vbuf, nullptr, nullptr);
  transpose_v<<<dim3(32, 64), 256, 0, stream>>>(vbuf, vtb);
  flash_attn<<<dim3(16, 64), 256, 0, stream>>>(qbuf, kbuf, vtb, aout);
  gemm_bt<1><<<dim3(8, 64), 256, 0, stream>>>(aout, wpb, nullptr, nullptr, nullptr, out, b_proj);
}